// Round 1
// baseline (1889.048 us; speedup 1.0000x reference)
//
#include <hip/hip_runtime.h>

// Problem constants
#define TOTAL_T 100
#define NB 256          // batch
#define NH 200          // hidden per (c,d) cell
#define NCD 9           // C*D
#define NJ (NB*NH)      // 51200 (b,h) pairs
#define KDIM 1024       // FS*FS

// GEMM tiling
#define BM 64
#define BN 64
#define BK 32
#define LDP 68          // padded LDS stride (16B-aligned rows, conflict-reducing)

// K1: inj[cd][m_local][h] = sum_i x[(m*3+c)*1024+i] * W_h[cd][h][i] + b_h[cd][h]
// A = x rows (t,b) flattened, stride 3*1024; B = W_h[c][d], both K-major (C = A*B^T).
__global__ __launch_bounds__(256) void gemm_inj(
    const float* __restrict__ x,   // already offset to chunk start
    const float* __restrict__ Wh,
    const float* __restrict__ bh,
    float* __restrict__ inj,
    int Mc)                        // rows in this chunk (Tc*256)
{
    __shared__ float As[BK][LDP];
    __shared__ float Bs[BK][LDP];
    const int m0 = blockIdx.x * BM;
    const int n0 = blockIdx.y * BN;
    const int cd = blockIdx.z;
    const int c  = cd / 3;
    const int tid = threadIdx.x;
    const int tr = tid >> 4;   // 0..15
    const int tc = tid & 15;   // 0..15

    const float* Bcd = Wh + (size_t)cd * NH * KDIM;
    float acc[4][4] = {{0.f}};

    for (int k0 = 0; k0 < KDIM; k0 += BK) {
        // Stage A and B tiles: 512 float4 each, 2 per thread each.
#pragma unroll
        for (int l = 0; l < 2; ++l) {
            int L  = tid + (l << 8);
            int r  = L >> 3;          // 0..63
            int kq = (L & 7) << 2;    // 0,4,...,28
            float4 a = *reinterpret_cast<const float4*>(
                x + ((size_t)(m0 + r) * 3 + c) * KDIM + k0 + kq);
            As[kq+0][r] = a.x; As[kq+1][r] = a.y;
            As[kq+2][r] = a.z; As[kq+3][r] = a.w;
            int h = n0 + r;
            float4 b = make_float4(0.f, 0.f, 0.f, 0.f);
            if (h < NH)
                b = *reinterpret_cast<const float4*>(
                    Bcd + (size_t)h * KDIM + k0 + kq);
            Bs[kq+0][r] = b.x; Bs[kq+1][r] = b.y;
            Bs[kq+2][r] = b.z; Bs[kq+3][r] = b.w;
        }
        __syncthreads();
#pragma unroll
        for (int kk = 0; kk < BK; ++kk) {
            float4 a4 = *reinterpret_cast<const float4*>(&As[kk][tr << 2]);
            float4 b4 = *reinterpret_cast<const float4*>(&Bs[kk][tc << 2]);
            float av[4] = {a4.x, a4.y, a4.z, a4.w};
            float bv[4] = {b4.x, b4.y, b4.z, b4.w};
#pragma unroll
            for (int i = 0; i < 4; ++i)
#pragma unroll
                for (int jj = 0; jj < 4; ++jj)
                    acc[i][jj] += av[i] * bv[jj];
        }
        __syncthreads();
    }

#pragma unroll
    for (int i = 0; i < 4; ++i) {
        int m = m0 + (tr << 2) + i;
#pragma unroll
        for (int jj = 0; jj < 4; ++jj) {
            int h = n0 + (tc << 2) + jj;
            if (h < NH)
                inj[((size_t)cd * Mc + m) * NH + h] = acc[i][jj] + bh[cd * NH + h];
        }
    }
}

// K2: per-(b,h) thread owns 9 LIF cells; scan Tc steps, emit summed spikes z.
__global__ __launch_bounds__(256) void scan_hidden(
    const float* __restrict__ inj,  // [cd][t_local][j]
    float* __restrict__ z,          // [t_local][j]
    float* __restrict__ vhs, float* __restrict__ ihs,  // [cd][j]
    int Tc, int first)
{
    int j = blockIdx.x * 256 + threadIdx.x;   // < NJ
    float vh[9], ih[9];
    if (first) {
#pragma unroll
        for (int cd = 0; cd < 9; ++cd) { vh[cd] = 0.f; ih[cd] = 0.f; }
    } else {
#pragma unroll
        for (int cd = 0; cd < 9; ++cd) {
            vh[cd] = vhs[cd * NJ + j];
            ih[cd] = ihs[cd * NJ + j];
        }
    }
    for (int t = 0; t < Tc; ++t) {
        float iv[9];
#pragma unroll
        for (int cd = 0; cd < 9; ++cd)
            iv[cd] = inj[((size_t)cd * Tc + t) * NJ + j];
        float zs = 0.f;
#pragma unroll
        for (int cd = 0; cd < 9; ++cd) {
            float vd = vh[cd] + 0.1f * (ih[cd] - vh[cd]);  // uses OLD ih
            ih[cd] = 0.8f * ih[cd] + iv[cd];
            if (vd > 1.0f) { zs += 1.f; vh[cd] = 0.f; }
            else           { vh[cd] = vd; }
        }
        z[(size_t)t * NJ + j] = zs;
    }
#pragma unroll
    for (int cd = 0; cd < 9; ++cd) {
        vhs[cd * NJ + j] = vh[cd];
        ihs[cd * NJ + j] = ih[cd];
    }
}

// K3: one block per batch b; threads 0..39 = (o,n) readout integrators.
__global__ __launch_bounds__(64) void scan_out(
    const float* __restrict__ z,    // [t_local][b][h]
    const float* __restrict__ Wo,   // [o][n][k]
    const float* __restrict__ bo,   // [o][n]
    float* __restrict__ out,        // [t][b][n]
    float* __restrict__ ios, float* __restrict__ vos,  // [b][40]
    int t0, int Tc, int first)
{
    int b = blockIdx.x;
    int tid = threadIdx.x;
    __shared__ float zsh[NH];
    __shared__ float vsh[40];
    int o = tid / 10, n = tid % 10;
    float w[50];
    float io = 0.f, vo = 0.f, bov = 0.f;
    if (tid < 40) {
#pragma unroll
        for (int k = 0; k < 50; ++k) w[k] = Wo[(o * 10 + n) * 50 + k];
        bov = bo[o * 10 + n];
        if (!first) { io = ios[b * 40 + tid]; vo = vos[b * 40 + tid]; }
    }
    for (int t = 0; t < Tc; ++t) {
        for (int h = tid; h < NH; h += 64)
            zsh[h] = z[((size_t)t * NB + b) * NH + h];
        __syncthreads();
        if (tid < 40) {
            float dot = 0.f;
#pragma unroll
            for (int k = 0; k < 50; ++k) dot += zsh[o * 50 + k] * w[k];
            vo = vo + 0.1f * (io - vo);      // old io
            io = 0.8f * io + dot + bov;
            vsh[tid] = vo;
        }
        __syncthreads();
        if (tid < 10)
            out[((size_t)(t0 + t) * NB + b) * 10 + tid] =
                vsh[tid] + vsh[10 + tid] + vsh[20 + tid] + vsh[30 + tid];
        __syncthreads();
    }
    if (tid < 40) { ios[b * 40 + tid] = io; vos[b * 40 + tid] = vo; }
}

extern "C" void kernel_launch(void* const* d_in, const int* in_sizes, int n_in,
                              void* d_out, int out_size, void* d_ws, size_t ws_size,
                              hipStream_t stream) {
    (void)in_sizes; (void)n_in; (void)out_size;
    const float* x  = (const float*)d_in[0];
    const float* Wh = (const float*)d_in[1];
    const float* bh = (const float*)d_in[2];
    const float* Wo = (const float*)d_in[3];
    const float* bo = (const float*)d_in[4];
    float* out = (float*)d_out;

    // ws layout: [vh states][ih states][io states][vo states][inj chunk][z chunk]
    float* vhs  = (float*)d_ws;          // 9*NJ
    float* ihs  = vhs + 9 * NJ;          // 9*NJ
    float* ios  = ihs + 9 * NJ;          // NB*40
    float* vos  = ios + NB * 40;         // NB*40
    float* base = vos + NB * 40;

    size_t fixed = ((size_t)9 * NJ * 2 + (size_t)NB * 40 * 2) * 4;
    int Tc = 1;
    const int divs[9] = {100, 50, 25, 20, 10, 5, 4, 2, 1};
    for (int i = 0; i < 9; ++i) {
        size_t need = fixed + (size_t)divs[i] * NJ * 10 * 4;  // 9 inj + 1 z per t
        if (need <= ws_size) { Tc = divs[i]; break; }
    }
    float* inj  = base;
    float* zbuf = inj + (size_t)9 * Tc * NJ;

    for (int t0 = 0; t0 < TOTAL_T; t0 += Tc) {
        int Mc = Tc * NB;
        gemm_inj<<<dim3(Mc / BM, (NH + BN - 1) / BN, NCD), 256, 0, stream>>>(
            x + (size_t)t0 * NB * 3 * KDIM, Wh, bh, inj, Mc);
        scan_hidden<<<NJ / 256, 256, 0, stream>>>(inj, zbuf, vhs, ihs, Tc, t0 == 0);
        scan_out<<<NB, 64, 0, stream>>>(zbuf, Wo, bo, out, ios, vos, t0, Tc, t0 == 0);
    }
}

// Round 2
// 926.892 us; speedup vs baseline: 2.0380x; 2.0380x over previous
//
#include <hip/hip_runtime.h>
#include <stdint.h>

// Problem constants
#define TOTAL_T 100
#define NB 256          // batch
#define NH 200          // hidden per (c,d) cell
#define NCD 9           // C*D
#define NJ (NB*NH)      // 51200
#define KDIM 1024       // FS*FS
#define NEFF 600        // d*200+h per c
#define NPAD 640        // 5 tiles of 128

// GEMM tiling
#define BM 128
#define BN 128
#define BK 32
#define LDK 40          // padded bf16 row stride (80 B)

typedef short bf16x8 __attribute__((ext_vector_type(8)));
typedef float f32x4  __attribute__((ext_vector_type(4)));

// Exact 3-limb bf16 truncation split of 4 fp32, packed little-endian pairs.
__device__ inline void split_pack4(const float4 v, uint32_t hw[2], uint32_t mw[2], uint32_t lw[2]) {
    float a[4] = {v.x, v.y, v.z, v.w};
    uint32_t hb[4], mb[4], lb[4];
#pragma unroll
    for (int i = 0; i < 4; ++i) {
        uint32_t ua = __float_as_uint(a[i]);
        hb[i] = ua & 0xffff0000u;
        float r = a[i] - __uint_as_float(hb[i]);     // exact
        uint32_t ur = __float_as_uint(r);
        mb[i] = ur & 0xffff0000u;
        float r2 = r - __uint_as_float(mb[i]);       // exact, <=8 sig bits left
        lb[i] = __float_as_uint(r2) & 0xffff0000u;   // exact bf16
    }
    hw[0] = (hb[0] >> 16) | hb[1]; hw[1] = (hb[2] >> 16) | hb[3];
    mw[0] = (mb[0] >> 16) | mb[1]; mw[1] = (mb[2] >> 16) | mb[3];
    lw[0] = (lb[0] >> 16) | lb[1]; lw[1] = (lb[2] >> 16) | lb[3];
}

// inj[(c*3+d)*Mc + m][h] = sum_k x[m][c][k] * Wh[c][d*200+h][k] + bh
// A rows: x chunk (Mc rows, channel c slice). B rows: Wh c-slice (600 rows, pad 640).
__global__ __launch_bounds__(256, 2) void gemm_inj_mfma(
    const float* __restrict__ x,    // chunk base
    const float* __restrict__ Wh,
    const float* __restrict__ bh,
    float* __restrict__ inj,
    int Mc)
{
    __shared__ __align__(16) unsigned short Ah[BM][LDK], Am[BM][LDK], Al[BM][LDK];
    __shared__ __align__(16) unsigned short Bh[BN][LDK], Bm[BN][LDK], Bl[BN][LDK];

    const int tid  = threadIdx.x;
    const int lane = tid & 63;
    const int w    = tid >> 6;            // 4 waves, 2x2
    const int mbase = (w >> 1) * 64;
    const int nbase = (w & 1) * 64;
    const int n0 = blockIdx.x * BN;       // 0..512
    const int m0 = blockIdx.y * BM;
    const int c  = blockIdx.z;

    f32x4 acc[4][4];
#pragma unroll
    for (int i = 0; i < 4; ++i)
#pragma unroll
        for (int j = 0; j < 4; ++j) acc[i][j] = (f32x4)0.f;

    // per-thread staging map: L = tid + 256*l -> row = L>>3 (0..127), kq = (L&7)*4
    const int srow = tid >> 3;
    const int skq  = (tid & 7) << 2;

    for (int k0 = 0; k0 < KDIM; k0 += BK) {
        float4 av[4], bv[4];
#pragma unroll
        for (int l = 0; l < 4; ++l) {
            int row = srow + (l << 5);
            av[l] = *reinterpret_cast<const float4*>(
                x + ((size_t)(m0 + row) * 3 + c) * KDIM + k0 + skq);
            int nrow = n0 + row;
            if (nrow < NEFF)
                bv[l] = *reinterpret_cast<const float4*>(
                    Wh + ((size_t)c * NEFF + nrow) * KDIM + k0 + skq);
            else
                bv[l] = make_float4(0.f, 0.f, 0.f, 0.f);
        }
        __syncthreads();   // previous iteration's frag reads complete
#pragma unroll
        for (int l = 0; l < 4; ++l) {
            int row = srow + (l << 5);
            uint32_t hw[2], mw[2], lw[2];
            split_pack4(av[l], hw, mw, lw);
            *reinterpret_cast<uint2*>(&Ah[row][skq]) = make_uint2(hw[0], hw[1]);
            *reinterpret_cast<uint2*>(&Am[row][skq]) = make_uint2(mw[0], mw[1]);
            *reinterpret_cast<uint2*>(&Al[row][skq]) = make_uint2(lw[0], lw[1]);
            split_pack4(bv[l], hw, mw, lw);
            *reinterpret_cast<uint2*>(&Bh[row][skq]) = make_uint2(hw[0], hw[1]);
            *reinterpret_cast<uint2*>(&Bm[row][skq]) = make_uint2(mw[0], mw[1]);
            *reinterpret_cast<uint2*>(&Bl[row][skq]) = make_uint2(lw[0], lw[1]);
        }
        __syncthreads();

        // fragment byte offset: row*(LDK*2) + (lane>>4)*16
        const int akoff = ((lane >> 4) << 3);
        bf16x8 afh[4], afm[4], afl[4];
#pragma unroll
        for (int mi = 0; mi < 4; ++mi) {
            int r = mbase + (mi << 4) + (lane & 15);
            size_t off = ((size_t)r * LDK + akoff) * 2;
            afh[mi] = *reinterpret_cast<const bf16x8*>((const char*)&Ah[0][0] + off);
            afm[mi] = *reinterpret_cast<const bf16x8*>((const char*)&Am[0][0] + off);
            afl[mi] = *reinterpret_cast<const bf16x8*>((const char*)&Al[0][0] + off);
        }
#pragma unroll
        for (int ni = 0; ni < 4; ++ni) {
            int r = nbase + (ni << 4) + (lane & 15);
            size_t off = ((size_t)r * LDK + akoff) * 2;
            bf16x8 bfh = *reinterpret_cast<const bf16x8*>((const char*)&Bh[0][0] + off);
            bf16x8 bfm = *reinterpret_cast<const bf16x8*>((const char*)&Bm[0][0] + off);
            bf16x8 bfl = *reinterpret_cast<const bf16x8*>((const char*)&Bl[0][0] + off);
#pragma unroll
            for (int mi = 0; mi < 4; ++mi) {
                f32x4 a = acc[mi][ni];
                a = __builtin_amdgcn_mfma_f32_16x16x32_bf16(afh[mi], bfh, a, 0, 0, 0);
                a = __builtin_amdgcn_mfma_f32_16x16x32_bf16(afh[mi], bfm, a, 0, 0, 0);
                a = __builtin_amdgcn_mfma_f32_16x16x32_bf16(afm[mi], bfh, a, 0, 0, 0);
                a = __builtin_amdgcn_mfma_f32_16x16x32_bf16(afm[mi], bfm, a, 0, 0, 0);
                a = __builtin_amdgcn_mfma_f32_16x16x32_bf16(afh[mi], bfl, a, 0, 0, 0);
                a = __builtin_amdgcn_mfma_f32_16x16x32_bf16(afl[mi], bfh, a, 0, 0, 0);
                acc[mi][ni] = a;
            }
        }
    }

    // C layout (m89): col = lane&15 (N), row = (lane>>4)*4 + reg (M)
#pragma unroll
    for (int ni = 0; ni < 4; ++ni) {
        int ncol = n0 + nbase + (ni << 4) + (lane & 15);
        if (ncol >= NEFF) continue;
        int d = ncol / 200;
        int h = ncol - d * 200;
        float bias = bh[c * NEFF + ncol];
        size_t obase = (size_t)(c * 3 + d) * Mc;
#pragma unroll
        for (int mi = 0; mi < 4; ++mi) {
            int mrow = m0 + mbase + (mi << 4) + ((lane >> 4) << 2);
#pragma unroll
            for (int r = 0; r < 4; ++r)
                inj[(obase + mrow + r) * NH + h] = acc[mi][ni][r] + bias;
        }
    }
}

// K2: per-(b,h) thread owns 9 LIF cells; scan Tc steps, emit summed spikes z.
__global__ __launch_bounds__(256) void scan_hidden(
    const float* __restrict__ inj,  // [cd][t_local][j]
    float* __restrict__ z,          // [t_local][j]
    float* __restrict__ vhs, float* __restrict__ ihs,  // [cd][j]
    int Tc, int first)
{
    int j = blockIdx.x * 256 + threadIdx.x;
    float vh[9], ih[9];
    if (first) {
#pragma unroll
        for (int cd = 0; cd < 9; ++cd) { vh[cd] = 0.f; ih[cd] = 0.f; }
    } else {
#pragma unroll
        for (int cd = 0; cd < 9; ++cd) {
            vh[cd] = vhs[cd * NJ + j];
            ih[cd] = ihs[cd * NJ + j];
        }
    }
    for (int t = 0; t < Tc; ++t) {
        float iv[9];
#pragma unroll
        for (int cd = 0; cd < 9; ++cd)
            iv[cd] = inj[((size_t)cd * Tc + t) * NJ + j];
        float zs = 0.f;
#pragma unroll
        for (int cd = 0; cd < 9; ++cd) {
            float vd = vh[cd] + 0.1f * (ih[cd] - vh[cd]);  // uses OLD ih
            ih[cd] = 0.8f * ih[cd] + iv[cd];
            if (vd > 1.0f) { zs += 1.f; vh[cd] = 0.f; }
            else           { vh[cd] = vd; }
        }
        z[(size_t)t * NJ + j] = zs;
    }
#pragma unroll
    for (int cd = 0; cd < 9; ++cd) {
        vhs[cd * NJ + j] = vh[cd];
        ihs[cd * NJ + j] = ih[cd];
    }
}

// K3: one block per batch b; threads 0..39 = (o,n) readout integrators.
__global__ __launch_bounds__(64) void scan_out(
    const float* __restrict__ z,    // [t_local][b][h]
    const float* __restrict__ Wo,   // [o][n][k]
    const float* __restrict__ bo,   // [o][n]
    float* __restrict__ out,        // [t][b][n]
    float* __restrict__ ios, float* __restrict__ vos,  // [b][40]
    int t0, int Tc, int first)
{
    int b = blockIdx.x;
    int tid = threadIdx.x;
    __shared__ float zsh[NH];
    __shared__ float vsh[40];
    int o = tid / 10, n = tid % 10;
    float w[50];
    float io = 0.f, vo = 0.f, bov = 0.f;
    if (tid < 40) {
#pragma unroll
        for (int k = 0; k < 50; ++k) w[k] = Wo[(o * 10 + n) * 50 + k];
        bov = bo[o * 10 + n];
        if (!first) { io = ios[b * 40 + tid]; vo = vos[b * 40 + tid]; }
    }
    for (int t = 0; t < Tc; ++t) {
        for (int h = tid; h < NH; h += 64)
            zsh[h] = z[((size_t)t * NB + b) * NH + h];
        __syncthreads();
        if (tid < 40) {
            float dot = 0.f;
#pragma unroll
            for (int k = 0; k < 50; ++k) dot += zsh[o * 50 + k] * w[k];
            vo = vo + 0.1f * (io - vo);      // old io
            io = 0.8f * io + dot + bov;
            vsh[tid] = vo;
        }
        __syncthreads();
        if (tid < 10)
            out[((size_t)(t0 + t) * NB + b) * 10 + tid] =
                vsh[tid] + vsh[10 + tid] + vsh[20 + tid] + vsh[30 + tid];
        __syncthreads();
    }
    if (tid < 40) { ios[b * 40 + tid] = io; vos[b * 40 + tid] = vo; }
}

extern "C" void kernel_launch(void* const* d_in, const int* in_sizes, int n_in,
                              void* d_out, int out_size, void* d_ws, size_t ws_size,
                              hipStream_t stream) {
    (void)in_sizes; (void)n_in; (void)out_size;
    const float* x  = (const float*)d_in[0];
    const float* Wh = (const float*)d_in[1];
    const float* bh = (const float*)d_in[2];
    const float* Wo = (const float*)d_in[3];
    const float* bo = (const float*)d_in[4];
    float* out = (float*)d_out;

    // ws layout: [vh][ih][io][vo][inj chunk][z chunk]
    float* vhs  = (float*)d_ws;          // 9*NJ
    float* ihs  = vhs + 9 * NJ;          // 9*NJ
    float* ios  = ihs + 9 * NJ;          // NB*40
    float* vos  = ios + NB * 40;         // NB*40
    float* inj  = vos + NB * 40;

    size_t fixed = ((size_t)9 * NJ * 2 + (size_t)NB * 40 * 2) * 4;
    size_t per_t = (size_t)NB * (9 * NH * 4 + NH * 4);   // inj + z per step
    int Tc = 1;
    for (int t = TOTAL_T; t >= 1; --t) {
        if (fixed + (size_t)t * per_t <= ws_size) { Tc = t; break; }
    }

    for (int t0 = 0; t0 < TOTAL_T; t0 += Tc) {
        int tc = (TOTAL_T - t0 < Tc) ? (TOTAL_T - t0) : Tc;
        int Mc = tc * NB;
        float* zbuf = inj + (size_t)9 * Mc * NH;
        gemm_inj_mfma<<<dim3(NPAD / BN, Mc / BM, 3), 256, 0, stream>>>(
            x + (size_t)t0 * NB * 3 * KDIM, Wh, bh, inj, Mc);
        scan_hidden<<<NJ / 256, 256, 0, stream>>>(inj, zbuf, vhs, ihs, tc, t0 == 0);
        scan_out<<<NB, 64, 0, stream>>>(zbuf, Wo, bo, out, ios, vos, t0, tc, t0 == 0);
    }
}

// Round 3
// 548.733 us; speedup vs baseline: 3.4426x; 1.6892x over previous
//
#include <hip/hip_runtime.h>
#include <stdint.h>

// Problem constants
#define TOTAL_T 100
#define NB 256          // batch
#define NH 200          // hidden per (c,d) cell
#define NCD 9           // C*D
#define NJ (NB*NH)      // 51200
#define KDIM 1024       // FS*FS
#define NEFF 600        // d*200+h per c
#define NPAD 640        // 5 tiles of 128
#define NTILES 5
#define KBLKS 32        // KDIM/32

// GEMM tiling
#define BM 128
#define BN 128
#define BK 32
#define LDK 40          // padded A row stride in halves (80 B)

// Pre-split Wh limb array: [c][kb][nt][kg][row][8] halves, 4096 halves per (c,kb,nt) chunk
#define WCHUNK 4096
#define NWHALF (3 * KBLKS * NTILES * WCHUNK)   // 1,966,080 ushorts = 3.93 MB

typedef _Float16 f16x8 __attribute__((ext_vector_type(8)));
typedef float    f32x4 __attribute__((ext_vector_type(4)));
typedef __attribute__((address_space(3))) uint32_t as3_u32;
typedef __attribute__((address_space(1))) uint32_t as1_u32;

// ---------------- P2: pre-split Wh into fp16 hi/mid limbs, tiled layout ---------
__global__ __launch_bounds__(256) void presplit_wh(
    const float* __restrict__ Wh, unsigned short* __restrict__ WH,
    unsigned short* __restrict__ WM)
{
    int idx = blockIdx.x * 256 + threadIdx.x;      // over 3*640*1024
    if (idx >= 3 * NPAD * KDIM) return;
    int k = idx & (KDIM - 1);
    int n = (idx >> 10) % NPAD;
    int c = idx / (NPAD * KDIM);
    float v = 0.f;
    if (n < NEFF) v = Wh[((size_t)c * NEFF + n) * KDIM + k];
    _Float16 h = (_Float16)v;                      // RN
    float r = v - (float)h;                        // exact
    _Float16 m = (_Float16)r;                      // RN
    int kb = k >> 5, kg = (k >> 3) & 3, kj = k & 7;
    int nt = n >> 7, row = n & 127;
    size_t off = (((size_t)c * KBLKS + kb) * NTILES + nt) * WCHUNK
               + (kg * 128 + row) * 8 + kj;
    WH[off] = __builtin_bit_cast(unsigned short, h);
    WM[off] = __builtin_bit_cast(unsigned short, m);
}

// ---------------- K1: fp16 2-limb 3-product MFMA GEMM ---------------------------
// inj[(c*3+d)*Mc + m][h] = sum_k x[m][c][k] * Wh[c][d*200+h][k] + bh
__global__ __launch_bounds__(256, 3) void gemm_inj_mfma(
    const float* __restrict__ x,          // chunk base
    const unsigned short* __restrict__ WH,
    const unsigned short* __restrict__ WM,
    const float* __restrict__ bh,
    float* __restrict__ inj,
    int Mc)
{
    __shared__ __align__(16) unsigned short Ah[BM][LDK], Am[BM][LDK];   // 10 KB each
    __shared__ __align__(16) unsigned short Bh[4 * 128 * 8], Bm[4 * 128 * 8]; // 8 KB each

    const int tid  = threadIdx.x;
    const int lane = tid & 63;
    const int w    = tid >> 6;            // 4 waves, 2x2
    const int mbase = (w >> 1) * 64;
    const int nbase = (w & 1) * 64;
    const int nt = blockIdx.x;            // 0..4
    const int n0 = nt * BN;
    const int m0 = blockIdx.y * BM;
    const int c  = blockIdx.z;

    f32x4 acc[4][4];
#pragma unroll
    for (int i = 0; i < 4; ++i)
#pragma unroll
        for (int j = 0; j < 4; ++j) acc[i][j] = (f32x4)0.f;

    const int srow = tid >> 3;            // 0..31
    const int skq  = (tid & 7) << 2;      // 0,4,..,28 (halves)

    // per-(c,nt) limb chunk base; advance by NTILES*WCHUNK per kb
    const unsigned short* bhp = WH + ((size_t)c * KBLKS * NTILES + nt) * WCHUNK;
    const unsigned short* bmp = WM + ((size_t)c * KBLKS * NTILES + nt) * WCHUNK;

    for (int kb = 0; kb < KBLKS; ++kb) {
        // A: reg-stage 4 rows x float4
        float4 av[4];
#pragma unroll
        for (int l = 0; l < 4; ++l) {
            int row = srow + (l << 5);
            av[l] = *reinterpret_cast<const float4*>(
                x + ((size_t)(m0 + row) * 3 + c) * KDIM + (kb << 5) + skq);
        }
        __syncthreads();   // previous iteration's frag reads complete

        // B: async global->LDS, linear copy of pre-tiled chunk (8 KB per limb)
#pragma unroll
        for (int i = 0; i < 2; ++i) {
            int seg = (i << 2) + w;                      // 0..7, 1 KB each
            __builtin_amdgcn_global_load_lds(
                (const as1_u32*)(bhp + ((seg << 6) + lane) * 8),
                (as3_u32*)&Bh[seg << 9], 16, 0, 0);
            __builtin_amdgcn_global_load_lds(
                (const as1_u32*)(bmp + ((seg << 6) + lane) * 8),
                (as3_u32*)&Bm[seg << 9], 16, 0, 0);
        }
        bhp += NTILES * WCHUNK;
        bmp += NTILES * WCHUNK;

        // A: split fp32 -> (hi, mid) fp16 RN limbs, write to padded LDS
#pragma unroll
        for (int l = 0; l < 4; ++l) {
            int row = srow + (l << 5);
            float a[4] = {av[l].x, av[l].y, av[l].z, av[l].w};
            uint32_t hw[2], mw[2];
#pragma unroll
            for (int p = 0; p < 2; ++p) {
                _Float16 h0 = (_Float16)a[2 * p];
                _Float16 h1 = (_Float16)a[2 * p + 1];
                float r0 = a[2 * p] - (float)h0;
                float r1 = a[2 * p + 1] - (float)h1;
                _Float16 m0v = (_Float16)r0;
                _Float16 m1v = (_Float16)r1;
                hw[p] = (uint32_t)__builtin_bit_cast(unsigned short, h0)
                      | ((uint32_t)__builtin_bit_cast(unsigned short, h1) << 16);
                mw[p] = (uint32_t)__builtin_bit_cast(unsigned short, m0v)
                      | ((uint32_t)__builtin_bit_cast(unsigned short, m1v) << 16);
            }
            *reinterpret_cast<uint2*>(&Ah[row][skq]) = make_uint2(hw[0], hw[1]);
            *reinterpret_cast<uint2*>(&Am[row][skq]) = make_uint2(mw[0], mw[1]);
        }
        __syncthreads();   // drains vmcnt (B tiles) + lgkm (A writes)

        // fragments: lane needs halves k = (lane>>4)*8 + j
        const int kg   = lane >> 4;
        const int lrow = lane & 15;
        f16x8 afh[4], afm[4];
#pragma unroll
        for (int mi = 0; mi < 4; ++mi) {
            int r = mbase + (mi << 4) + lrow;
            afh[mi] = *reinterpret_cast<const f16x8*>(&Ah[r][kg << 3]);
            afm[mi] = *reinterpret_cast<const f16x8*>(&Am[r][kg << 3]);
        }
#pragma unroll
        for (int ni = 0; ni < 4; ++ni) {
            int r = nbase + (ni << 4) + lrow;
            int boff = ((kg << 7) + r) << 3;            // (kg*128 + r)*8 halves
            f16x8 bfh = *reinterpret_cast<const f16x8*>(&Bh[boff]);
            f16x8 bfm = *reinterpret_cast<const f16x8*>(&Bm[boff]);
#pragma unroll
            for (int mi = 0; mi < 4; ++mi) {
                f32x4 a = acc[mi][ni];
                a = __builtin_amdgcn_mfma_f32_16x16x32_f16(afh[mi], bfh, a, 0, 0, 0);
                a = __builtin_amdgcn_mfma_f32_16x16x32_f16(afh[mi], bfm, a, 0, 0, 0);
                a = __builtin_amdgcn_mfma_f32_16x16x32_f16(afm[mi], bfh, a, 0, 0, 0);
                acc[mi][ni] = a;
            }
        }
    }

    // C layout: col = lane&15 (N), row = (lane>>4)*4 + reg (M)
#pragma unroll
    for (int ni = 0; ni < 4; ++ni) {
        int ncol = n0 + nbase + (ni << 4) + (lane & 15);
        if (ncol >= NEFF) continue;
        int d = ncol / 200;
        int h = ncol - d * 200;
        float bias = bh[c * NEFF + ncol];
        size_t obase = (size_t)(c * 3 + d) * Mc;
#pragma unroll
        for (int mi = 0; mi < 4; ++mi) {
            int mrow = m0 + mbase + (mi << 4) + ((lane >> 4) << 2);
#pragma unroll
            for (int r = 0; r < 4; ++r)
                inj[(obase + mrow + r) * NH + h] = acc[mi][ni][r] + bias;
        }
    }
}

// K2: per-(b,h) thread owns 9 LIF cells; scan Tc steps, emit summed spikes z.
__global__ __launch_bounds__(256) void scan_hidden(
    const float* __restrict__ inj,  // [cd][t_local][j]
    float* __restrict__ z,          // [t_local][j]
    float* __restrict__ vhs, float* __restrict__ ihs,  // [cd][j]
    int Tc, int first)
{
    int j = blockIdx.x * 256 + threadIdx.x;
    float vh[9], ih[9];
    if (first) {
#pragma unroll
        for (int cd = 0; cd < 9; ++cd) { vh[cd] = 0.f; ih[cd] = 0.f; }
    } else {
#pragma unroll
        for (int cd = 0; cd < 9; ++cd) {
            vh[cd] = vhs[cd * NJ + j];
            ih[cd] = ihs[cd * NJ + j];
        }
    }
    for (int t = 0; t < Tc; ++t) {
        float iv[9];
#pragma unroll
        for (int cd = 0; cd < 9; ++cd)
            iv[cd] = inj[((size_t)cd * Tc + t) * NJ + j];
        float zs = 0.f;
#pragma unroll
        for (int cd = 0; cd < 9; ++cd) {
            float vd = vh[cd] + 0.1f * (ih[cd] - vh[cd]);  // uses OLD ih
            ih[cd] = 0.8f * ih[cd] + iv[cd];
            if (vd > 1.0f) { zs += 1.f; vh[cd] = 0.f; }
            else           { vh[cd] = vd; }
        }
        z[(size_t)t * NJ + j] = zs;
    }
#pragma unroll
    for (int cd = 0; cd < 9; ++cd) {
        vhs[cd * NJ + j] = vh[cd];
        ihs[cd * NJ + j] = ih[cd];
    }
}

// K3: one block per batch b; threads 0..39 = (o,n) readout integrators.
__global__ __launch_bounds__(64) void scan_out(
    const float* __restrict__ z,    // [t_local][b][h]
    const float* __restrict__ Wo,   // [o][n][k]
    const float* __restrict__ bo,   // [o][n]
    float* __restrict__ out,        // [t][b][n]
    float* __restrict__ ios, float* __restrict__ vos,  // [b][40]
    int t0, int Tc, int first)
{
    int b = blockIdx.x;
    int tid = threadIdx.x;
    __shared__ float zsh[NH];
    __shared__ float vsh[40];
    int o = tid / 10, n = tid % 10;
    float w[50];
    float io = 0.f, vo = 0.f, bov = 0.f;
    if (tid < 40) {
#pragma unroll
        for (int k = 0; k < 50; ++k) w[k] = Wo[(o * 10 + n) * 50 + k];
        bov = bo[o * 10 + n];
        if (!first) { io = ios[b * 40 + tid]; vo = vos[b * 40 + tid]; }
    }
    for (int t = 0; t < Tc; ++t) {
        for (int h = tid; h < NH; h += 64)
            zsh[h] = z[((size_t)t * NB + b) * NH + h];
        __syncthreads();
        if (tid < 40) {
            float dot = 0.f;
#pragma unroll
            for (int k = 0; k < 50; ++k) dot += zsh[o * 50 + k] * w[k];
            vo = vo + 0.1f * (io - vo);      // old io
            io = 0.8f * io + dot + bov;
            vsh[tid] = vo;
        }
        __syncthreads();
        if (tid < 10)
            out[((size_t)(t0 + t) * NB + b) * 10 + tid] =
                vsh[tid] + vsh[10 + tid] + vsh[20 + tid] + vsh[30 + tid];
        __syncthreads();
    }
    if (tid < 40) { ios[b * 40 + tid] = io; vos[b * 40 + tid] = vo; }
}

extern "C" void kernel_launch(void* const* d_in, const int* in_sizes, int n_in,
                              void* d_out, int out_size, void* d_ws, size_t ws_size,
                              hipStream_t stream) {
    (void)in_sizes; (void)n_in; (void)out_size;
    const float* x  = (const float*)d_in[0];
    const float* Wh = (const float*)d_in[1];
    const float* bh = (const float*)d_in[2];
    const float* Wo = (const float*)d_in[3];
    const float* bo = (const float*)d_in[4];
    float* out = (float*)d_out;

    // ws layout: [vh][ih][io][vo][WH limbs][WM limbs][inj chunk][z chunk]
    float* vhs  = (float*)d_ws;          // 9*NJ
    float* ihs  = vhs + 9 * NJ;          // 9*NJ
    float* ios  = ihs + 9 * NJ;          // NB*40
    float* vos  = ios + NB * 40;         // NB*40
    unsigned short* WHl = (unsigned short*)(vos + NB * 40);
    unsigned short* WMl = WHl + NWHALF;
    float* inj  = (float*)(WMl + NWHALF);

    size_t fixed = ((size_t)9 * NJ * 2 + (size_t)NB * 40 * 2) * 4
                 + (size_t)NWHALF * 2 * 2;
    size_t per_t = (size_t)NB * (9 * NH * 4 + NH * 4);   // inj + z per step
    int Tc = 1;
    for (int t = TOTAL_T; t >= 1; --t) {
        if (fixed + (size_t)t * per_t <= ws_size) { Tc = t; break; }
    }

    presplit_wh<<<(3 * NPAD * KDIM + 255) / 256, 256, 0, stream>>>(Wh, WHl, WMl);

    for (int t0 = 0; t0 < TOTAL_T; t0 += Tc) {
        int tc = (TOTAL_T - t0 < Tc) ? (TOTAL_T - t0) : Tc;
        int Mc = tc * NB;
        float* zbuf = inj + (size_t)9 * Mc * NH;
        gemm_inj_mfma<<<dim3(NTILES, Mc / BM, 3), 256, 0, stream>>>(
            x + (size_t)t0 * NB * 3 * KDIM, WHl, WMl, bh, inj, Mc);
        scan_hidden<<<NJ / 256, 256, 0, stream>>>(inj, zbuf, vhs, ihs, tc, t0 == 0);
        scan_out<<<NB, 64, 0, stream>>>(zbuf, Wo, bo, out, ios, vos, t0, tc, t0 == 0);
    }
}

// Round 4
// 454.317 us; speedup vs baseline: 4.1580x; 1.2078x over previous
//
#include <hip/hip_runtime.h>
#include <stdint.h>

// Problem constants
#define TOTAL_T 100
#define NB 256          // batch
#define NH 200          // hidden per (c,d) cell
#define NCD 9           // C*D
#define NJ (NB*NH)      // 51200
#define KDIM 1024       // FS*FS
#define NEFF 600        // d*200+h per c
#define NPAD 640        // 5 tiles of 128
#define NTILES 5
#define KBLKS 32        // KDIM/32

// GEMM tiling
#define BM 128
#define BN 128
#define BK 32
#define LDK 40          // padded A row stride in halves (80 B)

// Pre-split Wh limb array: [c][kb][nt][kg][row][8] halves, 4096 halves per (c,kb,nt) chunk
#define WCHUNK 4096
#define NWHALF (3 * KBLKS * NTILES * WCHUNK)   // 1,966,080 ushorts

typedef _Float16 f16x8 __attribute__((ext_vector_type(8)));
typedef float    f32x4 __attribute__((ext_vector_type(4)));
typedef __attribute__((address_space(3))) uint32_t as3_u32;
typedef __attribute__((address_space(1))) uint32_t as1_u32;

// ---------------- P2: pre-split Wh into fp16 hi/mid limbs, tiled layout ---------
__global__ __launch_bounds__(256) void presplit_wh(
    const float* __restrict__ Wh, unsigned short* __restrict__ WH,
    unsigned short* __restrict__ WM)
{
    int idx = blockIdx.x * 256 + threadIdx.x;      // over 3*640*1024
    if (idx >= 3 * NPAD * KDIM) return;
    int k = idx & (KDIM - 1);
    int n = (idx >> 10) % NPAD;
    int c = idx / (NPAD * KDIM);
    float v = 0.f;
    if (n < NEFF) v = Wh[((size_t)c * NEFF + n) * KDIM + k];
    _Float16 h = (_Float16)v;                      // RN
    float r = v - (float)h;                        // exact
    _Float16 m = (_Float16)r;                      // RN
    int kb = k >> 5, kg = (k >> 3) & 3, kj = k & 7;
    int nt = n >> 7, row = n & 127;
    size_t off = (((size_t)c * KBLKS + kb) * NTILES + nt) * WCHUNK
               + (kg * 128 + row) * 8 + kj;
    WH[off] = __builtin_bit_cast(unsigned short, h);
    WM[off] = __builtin_bit_cast(unsigned short, m);
}

// ---------------- K1: fp16 2-limb 3-product MFMA GEMM, 2-phase pipelined --------
__global__ __launch_bounds__(256, 3) void gemm_inj_mfma(
    const float* __restrict__ x,          // chunk base
    const unsigned short* __restrict__ WH,
    const unsigned short* __restrict__ WM,
    const float* __restrict__ bh,
    float* __restrict__ inj,
    int Mc, int MBlk)                     // MBlk = Mc/128
{
    __shared__ __align__(16) unsigned short Ah[BM][LDK], Am[BM][LDK];      // 20 KB
    __shared__ __align__(16) unsigned short Bh[2][4096], Bm[2][4096];      // 32 KB

    const int tid  = threadIdx.x;
    const int lane = tid & 63;
    const int w    = tid >> 6;            // 4 waves, 2x2
    const int mbase = (w >> 1) * 64;
    const int nbase = (w & 1) * 64;

    // XCD-aware bijective remap: hw id -> logical (c, m, nt), nt fastest.
    {
    }
    const int nblk = gridDim.x;
    const int hw   = blockIdx.x;
    const int xcd  = hw & 7, jj = hw >> 3;
    const int q = nblk >> 3, rr = nblk & 7;
    const int L = (xcd < rr ? xcd * (q + 1) : rr * (q + 1) + (xcd - rr) * q) + jj;
    const int c   = L / (NTILES * MBlk);
    const int rem = L - c * (NTILES * MBlk);
    const int mb  = rem / NTILES;
    const int nt  = rem - mb * NTILES;
    const int n0 = nt * BN;
    const int m0 = mb * BM;

    f32x4 acc[4][4];
#pragma unroll
    for (int i = 0; i < 4; ++i)
#pragma unroll
        for (int j = 0; j < 4; ++j) acc[i][j] = (f32x4)0.f;

    const int srow = tid >> 3;            // 0..31
    const int skq  = (tid & 7) << 2;      // 0,4,..,28 (halves)

    const unsigned short* bhp = WH + ((size_t)c * KBLKS * NTILES + nt) * WCHUNK;
    const unsigned short* bmp = WM + ((size_t)c * KBLKS * NTILES + nt) * WCHUNK;
    const float* xb = x + (size_t)m0 * 3 * KDIM + (size_t)c * KDIM + skq;

    float4 av[4];
    // ---- prologue: A[0] -> regs, B[0] -> buf 0
#pragma unroll
    for (int l = 0; l < 4; ++l)
        av[l] = *reinterpret_cast<const float4*>(xb + (size_t)(srow + (l << 5)) * 3 * KDIM);
#pragma unroll
    for (int i = 0; i < 2; ++i) {
        int seg = (i << 2) + w;
        __builtin_amdgcn_global_load_lds(
            (const as1_u32*)(bhp + ((seg << 6) + lane) * 8),
            (as3_u32*)&Bh[0][seg << 9], 16, 0, 0);
        __builtin_amdgcn_global_load_lds(
            (const as1_u32*)(bmp + ((seg << 6) + lane) * 8),
            (as3_u32*)&Bm[0][seg << 9], 16, 0, 0);
    }
    __syncthreads();                      // B[0] in LDS, av = A[0]

    // split A[0] -> LDS
#pragma unroll
    for (int l = 0; l < 4; ++l) {
        int row = srow + (l << 5);
        float a[4] = {av[l].x, av[l].y, av[l].z, av[l].w};
        uint32_t hw2[2], mw2[2];
#pragma unroll
        for (int p = 0; p < 2; ++p) {
            _Float16 h0 = (_Float16)a[2 * p];
            _Float16 h1 = (_Float16)a[2 * p + 1];
            float r0 = a[2 * p] - (float)h0;
            float r1 = a[2 * p + 1] - (float)h1;
            _Float16 m0v = (_Float16)r0;
            _Float16 m1v = (_Float16)r1;
            hw2[p] = (uint32_t)__builtin_bit_cast(unsigned short, h0)
                   | ((uint32_t)__builtin_bit_cast(unsigned short, h1) << 16);
            mw2[p] = (uint32_t)__builtin_bit_cast(unsigned short, m0v)
                   | ((uint32_t)__builtin_bit_cast(unsigned short, m1v) << 16);
        }
        *reinterpret_cast<uint2*>(&Ah[row][skq]) = make_uint2(hw2[0], hw2[1]);
        *reinterpret_cast<uint2*>(&Am[row][skq]) = make_uint2(mw2[0], mw2[1]);
    }
    __syncthreads();                      // A[0] visible

    int cur = 0;
    for (int kb = 0; kb < KBLKS; ++kb) {
        const bool more = (kb + 1 < KBLKS);
        // ---- issue next-tile loads FIRST (latency hides under this iter's compute)
        if (more) {
#pragma unroll
            for (int l = 0; l < 4; ++l)
                av[l] = *reinterpret_cast<const float4*>(
                    xb + (size_t)(srow + (l << 5)) * 3 * KDIM + ((kb + 1) << 5));
            const unsigned short* nbh = bhp + (size_t)(kb + 1) * NTILES * WCHUNK;
            const unsigned short* nbm = bmp + (size_t)(kb + 1) * NTILES * WCHUNK;
            int nb_ = cur ^ 1;
#pragma unroll
            for (int i = 0; i < 2; ++i) {
                int seg = (i << 2) + w;
                __builtin_amdgcn_global_load_lds(
                    (const as1_u32*)(nbh + ((seg << 6) + lane) * 8),
                    (as3_u32*)&Bh[nb_][seg << 9], 16, 0, 0);
                __builtin_amdgcn_global_load_lds(
                    (const as1_u32*)(nbm + ((seg << 6) + lane) * 8),
                    (as3_u32*)&Bm[nb_][seg << 9], 16, 0, 0);
            }
        }

        // ---- fragment reads for this tile
        const int kg   = lane >> 4;
        const int lrow = lane & 15;
        f16x8 afh[4], afm[4], bfh[4], bfm[4];
#pragma unroll
        for (int mi = 0; mi < 4; ++mi) {
            int r = mbase + (mi << 4) + lrow;
            afh[mi] = *reinterpret_cast<const f16x8*>(&Ah[r][kg << 3]);
            afm[mi] = *reinterpret_cast<const f16x8*>(&Am[r][kg << 3]);
        }
#pragma unroll
        for (int ni = 0; ni < 4; ++ni) {
            int r = nbase + (ni << 4) + lrow;
            int boff = ((kg << 7) + r) << 3;
            bfh[ni] = *reinterpret_cast<const f16x8*>(&Bh[cur][boff]);
            bfm[ni] = *reinterpret_cast<const f16x8*>(&Bm[cur][boff]);
        }
        // all waves' frag reads done -> safe to overwrite Ah/Am later this iter
        asm volatile("s_waitcnt lgkmcnt(0)" ::: "memory");
        __builtin_amdgcn_s_barrier();     // raw: does NOT drain vmcnt (prefetch lives)
        __builtin_amdgcn_sched_barrier(0);

        // ---- MFMA cluster (hides A-reg and B-gll latency)
        __builtin_amdgcn_s_setprio(1);
#pragma unroll
        for (int ni = 0; ni < 4; ++ni)
#pragma unroll
            for (int mi = 0; mi < 4; ++mi) {
                f32x4 a = acc[mi][ni];
                a = __builtin_amdgcn_mfma_f32_16x16x32_f16(afh[mi], bfh[ni], a, 0, 0, 0);
                a = __builtin_amdgcn_mfma_f32_16x16x32_f16(afh[mi], bfm[ni], a, 0, 0, 0);
                a = __builtin_amdgcn_mfma_f32_16x16x32_f16(afm[mi], bfh[ni], a, 0, 0, 0);
                acc[mi][ni] = a;
            }
        __builtin_amdgcn_s_setprio(0);

        // ---- split A[kb+1] (regs arrived during MFMA) -> LDS
        if (more) {
#pragma unroll
            for (int l = 0; l < 4; ++l) {
                int row = srow + (l << 5);
                float a[4] = {av[l].x, av[l].y, av[l].z, av[l].w};
                uint32_t hw2[2], mw2[2];
#pragma unroll
                for (int p = 0; p < 2; ++p) {
                    _Float16 h0 = (_Float16)a[2 * p];
                    _Float16 h1 = (_Float16)a[2 * p + 1];
                    float r0 = a[2 * p] - (float)h0;
                    float r1 = a[2 * p + 1] - (float)h1;
                    _Float16 m0v = (_Float16)r0;
                    _Float16 m1v = (_Float16)r1;
                    hw2[p] = (uint32_t)__builtin_bit_cast(unsigned short, h0)
                           | ((uint32_t)__builtin_bit_cast(unsigned short, h1) << 16);
                    mw2[p] = (uint32_t)__builtin_bit_cast(unsigned short, m0v)
                           | ((uint32_t)__builtin_bit_cast(unsigned short, m1v) << 16);
                }
                *reinterpret_cast<uint2*>(&Ah[row][skq]) = make_uint2(hw2[0], hw2[1]);
                *reinterpret_cast<uint2*>(&Am[row][skq]) = make_uint2(mw2[0], mw2[1]);
            }
        }
        __syncthreads();                  // drains vmcnt (B[kb+1] ready) + lgkm (A writes)
        cur ^= 1;
    }

    // C layout: col = lane&15 (N), row = (lane>>4)*4 + reg (M)
#pragma unroll
    for (int ni = 0; ni < 4; ++ni) {
        int ncol = n0 + nbase + (ni << 4) + (lane & 15);
        if (ncol >= NEFF) continue;
        int d = ncol / 200;
        int h = ncol - d * 200;
        float bias = bh[c * NEFF + ncol];
        size_t obase = (size_t)(c * 3 + d) * Mc;
#pragma unroll
        for (int mi = 0; mi < 4; ++mi) {
            int mrow = m0 + mbase + (mi << 4) + ((lane >> 4) << 2);
#pragma unroll
            for (int r = 0; r < 4; ++r)
                inj[(obase + mrow + r) * NH + h] = acc[mi][ni][r] + bias;
        }
    }
}

// K2: per-(b,h) thread owns 9 LIF cells; scan Tc steps, emit summed spikes z.
__global__ __launch_bounds__(256) void scan_hidden(
    const float* __restrict__ inj,  // [cd][t_local][j]
    float* __restrict__ z,          // [t_local][j]
    float* __restrict__ vhs, float* __restrict__ ihs,  // [cd][j]
    int Tc, int first)
{
    int j = blockIdx.x * 256 + threadIdx.x;
    float vh[9], ih[9];
    if (first) {
#pragma unroll
        for (int cd = 0; cd < 9; ++cd) { vh[cd] = 0.f; ih[cd] = 0.f; }
    } else {
#pragma unroll
        for (int cd = 0; cd < 9; ++cd) {
            vh[cd] = vhs[cd * NJ + j];
            ih[cd] = ihs[cd * NJ + j];
        }
    }
    float ivn[9];
#pragma unroll
    for (int cd = 0; cd < 9; ++cd)
        ivn[cd] = inj[(size_t)cd * Tc * NJ + j];
    for (int t = 0; t < Tc; ++t) {
        float iv[9];
#pragma unroll
        for (int cd = 0; cd < 9; ++cd) iv[cd] = ivn[cd];
        if (t + 1 < Tc) {
#pragma unroll
            for (int cd = 0; cd < 9; ++cd)
                ivn[cd] = inj[((size_t)cd * Tc + t + 1) * NJ + j];
        }
        float zs = 0.f;
#pragma unroll
        for (int cd = 0; cd < 9; ++cd) {
            float vd = vh[cd] + 0.1f * (ih[cd] - vh[cd]);  // uses OLD ih
            ih[cd] = 0.8f * ih[cd] + iv[cd];
            if (vd > 1.0f) { zs += 1.f; vh[cd] = 0.f; }
            else           { vh[cd] = vd; }
        }
        z[(size_t)t * NJ + j] = zs;
    }
#pragma unroll
    for (int cd = 0; cd < 9; ++cd) {
        vhs[cd * NJ + j] = vh[cd];
        ihs[cd * NJ + j] = ih[cd];
    }
}

// K3a: u[tb][o*10+n] = bo[o][n] + sum_k z[tb][o*50+k] * Wo[o][n][k]
__global__ __launch_bounds__(256) void compute_u(
    const float* __restrict__ z, const float* __restrict__ Wo,
    const float* __restrict__ bo, float* __restrict__ u, int total)
{
    int idx = blockIdx.x * 256 + threadIdx.x;
    if (idx >= total) return;
    int tb = idx / 40;
    int on = idx - tb * 40;
    int o = on / 10;
    const float* zr = z + (size_t)tb * NH + o * 50;
    const float* wr = Wo + on * 50;
    float dot = bo[on];
#pragma unroll
    for (int k = 0; k < 50; ++k) dot += zr[k] * wr[k];
    u[idx] = dot;
}

// K3b: per-(b,n) thread scans 4 output leaky integrators over Tc steps.
__global__ __launch_bounds__(256) void scan_readout(
    const float* __restrict__ u,    // [t][b][40]
    float* __restrict__ out,        // [t][b][10]
    float* __restrict__ ios, float* __restrict__ vos,  // [b][40]
    int t0, int Tc, int first)
{
    int idx = blockIdx.x * 256 + threadIdx.x;   // over NB*10
    if (idx >= NB * 10) return;
    int b = idx / 10, n = idx - b * 10;
    float io[4], vo[4];
#pragma unroll
    for (int o = 0; o < 4; ++o) {
        if (first) { io[o] = 0.f; vo[o] = 0.f; }
        else { io[o] = ios[b * 40 + o * 10 + n]; vo[o] = vos[b * 40 + o * 10 + n]; }
    }
    float un[4];
#pragma unroll
    for (int o = 0; o < 4; ++o) un[o] = u[(size_t)b * 40 + o * 10 + n];
    for (int t = 0; t < Tc; ++t) {
        float uc[4];
#pragma unroll
        for (int o = 0; o < 4; ++o) uc[o] = un[o];
        if (t + 1 < Tc) {
#pragma unroll
            for (int o = 0; o < 4; ++o)
                un[o] = u[((size_t)(t + 1) * NB + b) * 40 + o * 10 + n];
        }
        float s = 0.f;
#pragma unroll
        for (int o = 0; o < 4; ++o) {
            vo[o] = vo[o] + 0.1f * (io[o] - vo[o]);   // old io
            io[o] = 0.8f * io[o] + uc[o];
            s += vo[o];
        }
        out[((size_t)(t0 + t) * NB + b) * 10 + n] = s;
    }
#pragma unroll
    for (int o = 0; o < 4; ++o) {
        ios[b * 40 + o * 10 + n] = io[o];
        vos[b * 40 + o * 10 + n] = vo[o];
    }
}

extern "C" void kernel_launch(void* const* d_in, const int* in_sizes, int n_in,
                              void* d_out, int out_size, void* d_ws, size_t ws_size,
                              hipStream_t stream) {
    (void)in_sizes; (void)n_in; (void)out_size;
    const float* x  = (const float*)d_in[0];
    const float* Wh = (const float*)d_in[1];
    const float* bh = (const float*)d_in[2];
    const float* Wo = (const float*)d_in[3];
    const float* bo = (const float*)d_in[4];
    float* out = (float*)d_out;

    // ws layout: [vh][ih][io][vo][WH limbs][WM limbs][inj | z | u  per chunk]
    float* vhs  = (float*)d_ws;          // 9*NJ
    float* ihs  = vhs + 9 * NJ;          // 9*NJ
    float* ios  = ihs + 9 * NJ;          // NB*40
    float* vos  = ios + NB * 40;         // NB*40
    unsigned short* WHl = (unsigned short*)(vos + NB * 40);
    unsigned short* WMl = WHl + NWHALF;
    float* inj  = (float*)(WMl + NWHALF);

    size_t fixed = ((size_t)9 * NJ * 2 + (size_t)NB * 40 * 2) * 4
                 + (size_t)NWHALF * 2 * 2;
    size_t per_t = (size_t)NB * (9 * NH * 4 + NH * 4 + 40 * 4);  // inj + z + u
    int Tc = 1;
    for (int t = TOTAL_T; t >= 1; --t) {
        if (fixed + (size_t)t * per_t <= ws_size) { Tc = t; break; }
    }

    presplit_wh<<<(3 * NPAD * KDIM + 255) / 256, 256, 0, stream>>>(Wh, WHl, WMl);

    for (int t0 = 0; t0 < TOTAL_T; t0 += Tc) {
        int tc = (TOTAL_T - t0 < Tc) ? (TOTAL_T - t0) : Tc;
        int Mc = tc * NB;
        int MBlk = Mc / BM;                       // Mc = tc*256, BM=128 -> 2*tc
        float* zbuf = inj + (size_t)9 * Mc * NH;
        float* ubuf = zbuf + (size_t)Mc * NH;
        gemm_inj_mfma<<<NTILES * MBlk * 3, 256, 0, stream>>>(
            x + (size_t)t0 * NB * 3 * KDIM, WHl, WMl, bh, inj, Mc, MBlk);
        scan_hidden<<<NJ / 256, 256, 0, stream>>>(inj, zbuf, vhs, ihs, tc, t0 == 0);
        compute_u<<<(Mc * 40 + 255) / 256, 256, 0, stream>>>(
            zbuf, Wo, bo, ubuf, Mc * 40);
        scan_readout<<<(NB * 10 + 255) / 256, 256, 0, stream>>>(
            ubuf, out, ios, vos, t0, tc, t0 == 0);
    }
}

// Round 5
// 424.320 us; speedup vs baseline: 4.4519x; 1.0707x over previous
//
#include <hip/hip_runtime.h>
#include <stdint.h>

// Problem constants
#define TOTAL_T 100
#define NB 256          // batch
#define NH 200          // hidden per (c,d) cell
#define NCD 9           // C*D
#define NJ (NB*NH)      // 51200
#define KDIM 1024       // FS*FS
#define NEFF 600        // d*200+h per c
#define NPAD 640        // 5 tiles of 128
#define NTILES 5
#define KBLKS 32        // KDIM/32

// GEMM tiling
#define BM 128
#define BN 128
#define BK 32
#define AST 1040        // A kg-subtile stride in halves (128*8 + 8 pad -> +8 bank shift/kg)

// Pre-split Wh limb array: [c][kb][nt][kg][row][8] halves, 4096 halves per (c,kb,nt) chunk
#define WCHUNK 4096
#define NWHALF (3 * KBLKS * NTILES * WCHUNK)

typedef _Float16 f16x8 __attribute__((ext_vector_type(8)));
typedef float    f32x4 __attribute__((ext_vector_type(4)));
typedef __attribute__((address_space(3))) uint32_t as3_u32;
typedef __attribute__((address_space(1))) uint32_t as1_u32;

// ---------------- P2: pre-split Wh into fp16 hi/mid limbs, tiled layout ---------
__global__ __launch_bounds__(256) void presplit_wh(
    const float* __restrict__ Wh, unsigned short* __restrict__ WH,
    unsigned short* __restrict__ WM)
{
    int idx = blockIdx.x * 256 + threadIdx.x;      // over 3*640*1024
    if (idx >= 3 * NPAD * KDIM) return;
    int k = idx & (KDIM - 1);
    int n = (idx >> 10) % NPAD;
    int c = idx / (NPAD * KDIM);
    float v = 0.f;
    if (n < NEFF) v = Wh[((size_t)c * NEFF + n) * KDIM + k];
    _Float16 h = (_Float16)v;                      // RN
    float r = v - (float)h;                        // exact
    _Float16 m = (_Float16)r;                      // RN
    int kb = k >> 5, kg = (k >> 3) & 3, kj = k & 7;
    int nt = n >> 7, row = n & 127;
    size_t off = (((size_t)c * KBLKS + kb) * NTILES + nt) * WCHUNK
               + (kg * 128 + row) * 8 + kj;
    WH[off] = __builtin_bit_cast(unsigned short, h);
    WM[off] = __builtin_bit_cast(unsigned short, m);
}

// ---------------- K1: fp16 2-limb 3-product MFMA GEMM, phased K-step ------------
__global__ __launch_bounds__(256, 3) void gemm_inj_mfma(
    const float* __restrict__ x,          // chunk base
    const unsigned short* __restrict__ WH,
    const unsigned short* __restrict__ WM,
    const float* __restrict__ bh,
    float* __restrict__ inj,
    int Mc, int MBlk)                     // MBlk = Mc/128
{
    __shared__ __align__(16) unsigned short Ah[4 * AST], Am[4 * AST];       // ~16.6 KB
    __shared__ __align__(16) unsigned short Bh[2][4096], Bm[2][4096];       // 32 KB

    const int tid  = threadIdx.x;
    const int lane = tid & 63;
    const int w    = tid >> 6;            // 4 waves, 2x2
    const int mbase = (w >> 1) * 64;
    const int nbase = (w & 1) * 64;

    // XCD-aware bijective remap: hw id -> logical (c, mb, nt), nt fastest.
    const int nblk = gridDim.x;
    const int hw   = blockIdx.x;
    const int xcd  = hw & 7, jj = hw >> 3;
    const int q = nblk >> 3, rr = nblk & 7;
    const int L = (xcd < rr ? xcd * (q + 1) : rr * (q + 1) + (xcd - rr) * q) + jj;
    const int c   = L / (NTILES * MBlk);
    const int rem = L - c * (NTILES * MBlk);
    const int mb  = rem / NTILES;
    const int nt  = rem - mb * NTILES;
    const int n0 = nt * BN;
    const int m0 = mb * BM;

    f32x4 acc[4][4];
#pragma unroll
    for (int i = 0; i < 4; ++i)
#pragma unroll
        for (int j = 0; j < 4; ++j) acc[i][j] = (f32x4)0.f;

    const int srow = tid >> 3;            // 0..31
    const int skq  = (tid & 7) << 2;      // 0,4,..,28 (halves)
    const int kgw  = skq >> 3;            // write subtile
    const int kjw  = skq & 7;             // 0 or 4

    const unsigned short* bhp = WH + ((size_t)c * KBLKS * NTILES + nt) * WCHUNK;
    const unsigned short* bmp = WM + ((size_t)c * KBLKS * NTILES + nt) * WCHUNK;
    const float* xb = x + (size_t)m0 * 3 * KDIM + (size_t)c * KDIM + skq;

    float4 av[4];
    // ---- prologue: A[0] -> regs, B[0] -> buf 0
#pragma unroll
    for (int l = 0; l < 4; ++l)
        av[l] = *reinterpret_cast<const float4*>(xb + (size_t)(srow + (l << 5)) * 3 * KDIM);
#pragma unroll
    for (int i = 0; i < 2; ++i) {
        int seg = (i << 2) + w;
        __builtin_amdgcn_global_load_lds(
            (const as1_u32*)(bhp + ((seg << 6) + lane) * 8),
            (as3_u32*)&Bh[0][seg << 9], 16, 0, 0);
        __builtin_amdgcn_global_load_lds(
            (const as1_u32*)(bmp + ((seg << 6) + lane) * 8),
            (as3_u32*)&Bm[0][seg << 9], 16, 0, 0);
    }
    __syncthreads();                      // B[0] in LDS, av = A[0]

    // split A[0] -> LDS (subtiled layout)
#pragma unroll
    for (int l = 0; l < 4; ++l) {
        int row = srow + (l << 5);
        float a[4] = {av[l].x, av[l].y, av[l].z, av[l].w};
        uint32_t hw2[2], mw2[2];
#pragma unroll
        for (int p = 0; p < 2; ++p) {
            _Float16 h0 = (_Float16)a[2 * p];
            _Float16 h1 = (_Float16)a[2 * p + 1];
            float r0 = a[2 * p] - (float)h0;
            float r1 = a[2 * p + 1] - (float)h1;
            _Float16 m0v = (_Float16)r0;
            _Float16 m1v = (_Float16)r1;
            hw2[p] = (uint32_t)__builtin_bit_cast(unsigned short, h0)
                   | ((uint32_t)__builtin_bit_cast(unsigned short, h1) << 16);
            mw2[p] = (uint32_t)__builtin_bit_cast(unsigned short, m0v)
                   | ((uint32_t)__builtin_bit_cast(unsigned short, m1v) << 16);
        }
        int off = kgw * AST + row * 8 + kjw;
        *reinterpret_cast<uint2*>(&Ah[off]) = make_uint2(hw2[0], hw2[1]);
        *reinterpret_cast<uint2*>(&Am[off]) = make_uint2(mw2[0], mw2[1]);
    }
    __syncthreads();                      // A[0] visible

    const int kg   = lane >> 4;
    const int lrow = lane & 15;

    int cur = 0;
    for (int kb = 0; kb < KBLKS; ++kb) {
        const bool more = (kb + 1 < KBLKS);
        // ---- issue next-tile global loads FIRST (vmcnt; drained at end barrier)
        if (more) {
#pragma unroll
            for (int l = 0; l < 4; ++l)
                av[l] = *reinterpret_cast<const float4*>(
                    xb + (size_t)(srow + (l << 5)) * 3 * KDIM + ((kb + 1) << 5));
            const unsigned short* nbh = bhp + (size_t)(kb + 1) * NTILES * WCHUNK;
            const unsigned short* nbm = bmp + (size_t)(kb + 1) * NTILES * WCHUNK;
            int nb_ = cur ^ 1;
#pragma unroll
            for (int i = 0; i < 2; ++i) {
                int seg = (i << 2) + w;
                __builtin_amdgcn_global_load_lds(
                    (const as1_u32*)(nbh + ((seg << 6) + lane) * 8),
                    (as3_u32*)&Bh[nb_][seg << 9], 16, 0, 0);
                __builtin_amdgcn_global_load_lds(
                    (const as1_u32*)(nbm + ((seg << 6) + lane) * 8),
                    (as3_u32*)&Bm[nb_][seg << 9], 16, 0, 0);
            }
        }

        // ---- A frag reads (8 b128), pinned before B reads
        f16x8 afh[4], afm[4], bfh[4], bfm[4];
#pragma unroll
        for (int mi = 0; mi < 4; ++mi) {
            int off = kg * AST + (mbase + (mi << 4) + lrow) * 8;
            afh[mi] = *reinterpret_cast<const f16x8*>(&Ah[off]);
            afm[mi] = *reinterpret_cast<const f16x8*>(&Am[off]);
        }
        __builtin_amdgcn_sched_barrier(0);
        // ---- B0, B1 frag reads
#pragma unroll
        for (int ni = 0; ni < 2; ++ni) {
            int boff = ((kg << 7) + nbase + (ni << 4) + lrow) << 3;
            bfh[ni] = *reinterpret_cast<const f16x8*>(&Bh[cur][boff]);
            bfm[ni] = *reinterpret_cast<const f16x8*>(&Bm[cur][boff]);
        }
        __builtin_amdgcn_sched_barrier(0);
        asm volatile("s_waitcnt lgkmcnt(4)" ::: "memory");  // A frags complete
        __builtin_amdgcn_sched_barrier(0);
        __builtin_amdgcn_s_barrier();     // raw: A reads done; vmcnt prefetch lives on
        __builtin_amdgcn_sched_barrier(0);

        __builtin_amdgcn_s_setprio(1);
        // ---- phase 0: issue B2; wait B0; MFMA ni=0
        {
            int boff = ((kg << 7) + nbase + (2 << 4) + lrow) << 3;
            bfh[2] = *reinterpret_cast<const f16x8*>(&Bh[cur][boff]);
            bfm[2] = *reinterpret_cast<const f16x8*>(&Bm[cur][boff]);
        }
        asm volatile("s_waitcnt lgkmcnt(4)" ::: "memory");
        __builtin_amdgcn_sched_barrier(0);
#pragma unroll
        for (int mi = 0; mi < 4; ++mi) {
            f32x4 a = acc[mi][0];
            a = __builtin_amdgcn_mfma_f32_16x16x32_f16(afh[mi], bfh[0], a, 0, 0, 0);
            a = __builtin_amdgcn_mfma_f32_16x16x32_f16(afh[mi], bfm[0], a, 0, 0, 0);
            a = __builtin_amdgcn_mfma_f32_16x16x32_f16(afm[mi], bfh[0], a, 0, 0, 0);
            acc[mi][0] = a;
        }
        __builtin_amdgcn_sched_barrier(0);
        // ---- phase 1: issue B3; wait B1; MFMA ni=1
        {
            int boff = ((kg << 7) + nbase + (3 << 4) + lrow) << 3;
            bfh[3] = *reinterpret_cast<const f16x8*>(&Bh[cur][boff]);
            bfm[3] = *reinterpret_cast<const f16x8*>(&Bm[cur][boff]);
        }
        asm volatile("s_waitcnt lgkmcnt(4)" ::: "memory");
        __builtin_amdgcn_sched_barrier(0);
#pragma unroll
        for (int mi = 0; mi < 4; ++mi) {
            f32x4 a = acc[mi][1];
            a = __builtin_amdgcn_mfma_f32_16x16x32_f16(afh[mi], bfh[1], a, 0, 0, 0);
            a = __builtin_amdgcn_mfma_f32_16x16x32_f16(afh[mi], bfm[1], a, 0, 0, 0);
            a = __builtin_amdgcn_mfma_f32_16x16x32_f16(afm[mi], bfh[1], a, 0, 0, 0);
            acc[mi][1] = a;
        }
        __builtin_amdgcn_sched_barrier(0);
        // ---- phase 2: wait B2; MFMA ni=2
        asm volatile("s_waitcnt lgkmcnt(2)" ::: "memory");
        __builtin_amdgcn_sched_barrier(0);
#pragma unroll
        for (int mi = 0; mi < 4; ++mi) {
            f32x4 a = acc[mi][2];
            a = __builtin_amdgcn_mfma_f32_16x16x32_f16(afh[mi], bfh[2], a, 0, 0, 0);
            a = __builtin_amdgcn_mfma_f32_16x16x32_f16(afh[mi], bfm[2], a, 0, 0, 0);
            a = __builtin_amdgcn_mfma_f32_16x16x32_f16(afm[mi], bfh[2], a, 0, 0, 0);
            acc[mi][2] = a;
        }
        __builtin_amdgcn_sched_barrier(0);
        // ---- phase 3: wait B3; MFMA ni=3
        asm volatile("s_waitcnt lgkmcnt(0)" ::: "memory");
        __builtin_amdgcn_sched_barrier(0);
#pragma unroll
        for (int mi = 0; mi < 4; ++mi) {
            f32x4 a = acc[mi][3];
            a = __builtin_amdgcn_mfma_f32_16x16x32_f16(afh[mi], bfh[3], a, 0, 0, 0);
            a = __builtin_amdgcn_mfma_f32_16x16x32_f16(afh[mi], bfm[3], a, 0, 0, 0);
            a = __builtin_amdgcn_mfma_f32_16x16x32_f16(afm[mi], bfh[3], a, 0, 0, 0);
            acc[mi][3] = a;
        }
        __builtin_amdgcn_s_setprio(0);
        __builtin_amdgcn_sched_barrier(0);

        // ---- split A[kb+1] (regs arrived during MFMA) -> LDS
        if (more) {
#pragma unroll
            for (int l = 0; l < 4; ++l) {
                int row = srow + (l << 5);
                float a[4] = {av[l].x, av[l].y, av[l].z, av[l].w};
                uint32_t hw2[2], mw2[2];
#pragma unroll
                for (int p = 0; p < 2; ++p) {
                    _Float16 h0 = (_Float16)a[2 * p];
                    _Float16 h1 = (_Float16)a[2 * p + 1];
                    float r0 = a[2 * p] - (float)h0;
                    float r1 = a[2 * p + 1] - (float)h1;
                    _Float16 m0v = (_Float16)r0;
                    _Float16 m1v = (_Float16)r1;
                    hw2[p] = (uint32_t)__builtin_bit_cast(unsigned short, h0)
                           | ((uint32_t)__builtin_bit_cast(unsigned short, h1) << 16);
                    mw2[p] = (uint32_t)__builtin_bit_cast(unsigned short, m0v)
                           | ((uint32_t)__builtin_bit_cast(unsigned short, m1v) << 16);
                }
                int off = kgw * AST + row * 8 + kjw;
                *reinterpret_cast<uint2*>(&Ah[off]) = make_uint2(hw2[0], hw2[1]);
                *reinterpret_cast<uint2*>(&Am[off]) = make_uint2(mw2[0], mw2[1]);
            }
        }
        __syncthreads();                  // drains vmcnt (B[kb+1] ready) + lgkm (A writes)
        cur ^= 1;
    }

    // C layout: col = lane&15 (N), row = (lane>>4)*4 + reg (M)
#pragma unroll
    for (int ni = 0; ni < 4; ++ni) {
        int ncol = n0 + nbase + (ni << 4) + (lane & 15);
        if (ncol >= NEFF) continue;
        int d = ncol / 200;
        int h = ncol - d * 200;
        float bias = bh[c * NEFF + ncol];
        size_t obase = (size_t)(c * 3 + d) * Mc;
#pragma unroll
        for (int mi = 0; mi < 4; ++mi) {
            int mrow = m0 + mbase + (mi << 4) + ((lane >> 4) << 2);
#pragma unroll
            for (int r = 0; r < 4; ++r)
                inj[(obase + mrow + r) * NH + h] = acc[mi][ni][r] + bias;
        }
    }
}

// K2: fused per-batch scan: LIF neurons + readout dots + output integrators.
// One block per b; z and u never leave LDS.
__global__ __launch_bounds__(256) void scan_fused(
    const float* __restrict__ inj,  // [cd][t][b][h]
    const float* __restrict__ Wo,   // [40][50]
    const float* __restrict__ bo,   // [40]
    float* __restrict__ out,        // [t][b][10]
    float* __restrict__ vhs, float* __restrict__ ihs,   // [cd][j]
    float* __restrict__ ios, float* __restrict__ vos,   // [b][40]
    int t0, int Tc, int first)
{
    const int b = blockIdx.x;
    const int tid = threadIdx.x;
    __shared__ float zsh[NH];
    __shared__ float vsh[40];
    __shared__ float wsh[2000];
    __shared__ float bsh[40];

    for (int i = tid; i < 2000; i += 256) wsh[i] = Wo[i];
    if (tid < 40) bsh[tid] = bo[tid];

    const int j = b * NH + tid;
    float vh[9], ih[9];
    if (tid < NH) {
        if (first) {
#pragma unroll
            for (int cd = 0; cd < 9; ++cd) { vh[cd] = 0.f; ih[cd] = 0.f; }
        } else {
#pragma unroll
            for (int cd = 0; cd < 9; ++cd) {
                vh[cd] = vhs[cd * NJ + j];
                ih[cd] = ihs[cd * NJ + j];
            }
        }
    }
    float rio = 0.f, rvo = 0.f;
    if (tid < 40 && !first) { rio = ios[b * 40 + tid]; rvo = vos[b * 40 + tid]; }

    // depth-2 inj prefetch
    float ivc[9], ivn[9];
    if (tid < NH) {
#pragma unroll
        for (int cd = 0; cd < 9; ++cd)
            ivc[cd] = inj[((size_t)cd * Tc + 0) * NJ + j];
        if (Tc > 1) {
#pragma unroll
            for (int cd = 0; cd < 9; ++cd)
                ivn[cd] = inj[((size_t)cd * Tc + 1) * NJ + j];
        }
    }
    __syncthreads();   // wsh/bsh ready

    for (int t = 0; t < Tc; ++t) {
        // phase A: LIF step, spike sum -> zsh; rotate prefetch
        if (tid < NH) {
            float zs = 0.f;
#pragma unroll
            for (int cd = 0; cd < 9; ++cd) {
                float iv = ivc[cd];
                ivc[cd] = ivn[cd];
                float vd = vh[cd] + 0.1f * (ih[cd] - vh[cd]);  // OLD ih
                ih[cd] = 0.8f * ih[cd] + iv;
                if (vd > 1.0f) { zs += 1.f; vh[cd] = 0.f; }
                else           { vh[cd] = vd; }
            }
            zsh[tid] = zs;
            if (t + 2 < Tc) {
#pragma unroll
                for (int cd = 0; cd < 9; ++cd)
                    ivn[cd] = inj[((size_t)cd * Tc + t + 2) * NJ + j];
            }
        }
        __syncthreads();
        // phase B: 40 readout integrators
        if (tid < 40) {
            int o = tid / 10;
            float dot = bsh[tid];
            const float* wr = &wsh[tid * 50];
            const float* zr = &zsh[o * 50];
#pragma unroll
            for (int k = 0; k < 50; ++k) dot += zr[k] * wr[k];
            rvo = rvo + 0.1f * (rio - rvo);   // old io
            rio = 0.8f * rio + dot;
            vsh[tid] = rvo;
        }
        __syncthreads();
        // phase C: 10 output writes (vsh stable until next phase B)
        if (tid < 10)
            out[((size_t)(t0 + t) * NB + b) * 10 + tid] =
                vsh[tid] + vsh[10 + tid] + vsh[20 + tid] + vsh[30 + tid];
    }

    if (tid < NH) {
#pragma unroll
        for (int cd = 0; cd < 9; ++cd) {
            vhs[cd * NJ + j] = vh[cd];
            ihs[cd * NJ + j] = ih[cd];
        }
    }
    if (tid < 40) { ios[b * 40 + tid] = rio; vos[b * 40 + tid] = rvo; }
}

extern "C" void kernel_launch(void* const* d_in, const int* in_sizes, int n_in,
                              void* d_out, int out_size, void* d_ws, size_t ws_size,
                              hipStream_t stream) {
    (void)in_sizes; (void)n_in; (void)out_size;
    const float* x  = (const float*)d_in[0];
    const float* Wh = (const float*)d_in[1];
    const float* bh = (const float*)d_in[2];
    const float* Wo = (const float*)d_in[3];
    const float* bo = (const float*)d_in[4];
    float* out = (float*)d_out;

    // ws layout: [vh][ih][io][vo][WH limbs][WM limbs][inj chunk]
    float* vhs  = (float*)d_ws;          // 9*NJ
    float* ihs  = vhs + 9 * NJ;          // 9*NJ
    float* ios  = ihs + 9 * NJ;          // NB*40
    float* vos  = ios + NB * 40;         // NB*40
    unsigned short* WHl = (unsigned short*)(vos + NB * 40);
    unsigned short* WMl = WHl + NWHALF;
    float* inj  = (float*)(WMl + NWHALF);

    size_t fixed = ((size_t)9 * NJ * 2 + (size_t)NB * 40 * 2) * 4
                 + (size_t)NWHALF * 2 * 2;
    size_t per_t = (size_t)NB * 9 * NH * 4;   // inj only (z, u live in LDS)
    int Tc = 1;
    for (int t = TOTAL_T; t >= 1; --t) {
        if (fixed + (size_t)t * per_t <= ws_size) { Tc = t; break; }
    }

    presplit_wh<<<(3 * NPAD * KDIM + 255) / 256, 256, 0, stream>>>(Wh, WHl, WMl);

    for (int t0 = 0; t0 < TOTAL_T; t0 += Tc) {
        int tc = (TOTAL_T - t0 < Tc) ? (TOTAL_T - t0) : Tc;
        int Mc = tc * NB;
        int MBlk = Mc / BM;
        gemm_inj_mfma<<<NTILES * MBlk * 3, 256, 0, stream>>>(
            x + (size_t)t0 * NB * 3 * KDIM, WHl, WMl, bh, inj, Mc, MBlk);
        scan_fused<<<NB, 256, 0, stream>>>(
            inj, Wo, bo, out, vhs, ihs, ios, vos, t0, tc, t0 == 0);
    }
}